// Round 15
// baseline (912.030 us; speedup 1.0000x reference)
//
#include <hip/hip_runtime.h>
#include <hip/hip_bf16.h>

typedef __bf16 bf16_t;
typedef __bf16 bf16x8 __attribute__((ext_vector_type(8)));
typedef __bf16 bf16x4 __attribute__((ext_vector_type(4)));
typedef float floatx4 __attribute__((ext_vector_type(4)));

#define NB 2
#define NT 2048
#define NC 1024
#define NH 16
#define HD 64
#define BT (NB*NT)

// async global->LDS, 16B per lane, LDS dest = wave-uniform base + lane*16
#define GLL16(g, l) __builtin_amdgcn_global_load_lds( \
    (const __attribute__((address_space(1))) void*)(g), \
    (__attribute__((address_space(3))) void*)(l), 16, 0, 0)

// ---------------- convert x: fp32 -> bf16 (row-major copy) ----------------
__global__ void k_cvt_x(const float* __restrict__ x, bf16_t* __restrict__ xb, int n){
  int i = (blockIdx.x*blockDim.x + threadIdx.x)*4;
  if (i >= n) return;
  float4 v = *(const float4*)(x+i);
  bf16_t o[4] = {(bf16_t)v.x,(bf16_t)v.y,(bf16_t)v.z,(bf16_t)v.w};
  *(uint2*)(xb+i) = *(const uint2*)o;
}

// ------- transpose-convert: in fp32 [K][N] -> out bf16 [N][K] (tiled) -------
__global__ void k_cvt_t(const float* __restrict__ in, bf16_t* __restrict__ out, int K, int N){
  __shared__ float tile[32][33];
  int tid = threadIdx.x;
  int kt = blockIdx.y*32, nt = blockIdx.x*32;
  int row = tid>>3, c4 = (tid&7)*4;
  float4 v = *(const float4*)(in + (size_t)(kt+row)*N + nt + c4);
  tile[row][c4+0]=v.x; tile[row][c4+1]=v.y; tile[row][c4+2]=v.z; tile[row][c4+3]=v.w;
  __syncthreads();
  bf16_t o[4];
  #pragma unroll
  for (int i=0;i<4;i++) o[i] = (bf16_t)tile[c4+i][row];
  *(uint2*)(out + (size_t)(nt+row)*K + kt + c4) = *(const uint2*)o;
}

// ---- bf16 transpose of the V block of qkv: [t][2048+h*64+d] -> Vt[bh][d][t] ----
__global__ void k_trv(const bf16_t* __restrict__ qkv, bf16_t* __restrict__ Vt){
  __shared__ float tile[32][33];
  int tid = threadIdx.x;
  int bh = blockIdx.z; int b = bh>>4, h = bh&15;
  int t0 = blockIdx.y*32, d0 = blockIdx.x*32;
  int row = tid>>3, c4 = (tid&7)*4;
  bf16x4 v = *(const bf16x4*)(qkv + (size_t)(b*NT + t0 + row)*3072 + 2048 + h*HD + d0 + c4);
  #pragma unroll
  for (int i=0;i<4;i++) tile[row][c4+i] = (float)v[i];
  __syncthreads();
  bf16x4 o;
  #pragma unroll
  for (int i=0;i<4;i++) o[i] = (bf16_t)tile[c4+i][row];
  *(bf16x4*)(Vt + ((size_t)bh*HD + d0 + row)*NT + t0 + c4) = o;
}

// ---------------- bf16 MFMA GEMM: C[M][N] = A[M][K] * Bt[N][K]^T ----------------
// m97-style: BMx128 tile (BM=MI*32), BK=64, 4 waves each (MI*16)x64,
// global_load_lds staging, XOR-swizzled LDS (slot ^= row&7) via pre-swizzled source.
template<int MI, bool BIAS, bool OUTBF>
__global__ __launch_bounds__(256) void k_gemm(
    const bf16_t* __restrict__ A, const bf16_t* __restrict__ Bt,
    void* __restrict__ Cv, const float* __restrict__ bias, int M, int N, int K){
  constexpr int BM = MI*32;
  __shared__ __align__(16) bf16_t As[BM][64];
  __shared__ __align__(16) bf16_t Bs[128][64];
  int tid = threadIdx.x;
  int wave = tid>>6, lane = tid&63, quad = lane>>4, l15 = lane&15;
  int m0 = blockIdx.y*BM, n0 = blockIdx.x*128;
  int wm = (wave>>1)*(MI*16), wn = (wave&1)*64;
  floatx4 acc[MI][4];
  #pragma unroll
  for(int i=0;i<MI;i++)
    #pragma unroll
    for(int j=0;j<4;j++) acc[i][j] = (floatx4){0.f,0.f,0.f,0.f};
  int srow = lane>>3;                 // row within 8-row chunk
  int sslot = (lane&7) ^ srow;        // pre-swizzled 16B slot in source
  const bf16_t* Ag = A  + (size_t)(m0 + wave*(MI*8) + srow)*K + sslot*8;
  const bf16_t* Bg = Bt + (size_t)(n0 + wave*32 + srow)*K + sslot*8;
  int rs = l15 & 7;
  for (int k0=0; k0<K; k0+=64){
    #pragma unroll
    for (int i=0;i<MI;i++)
      GLL16(Ag + (size_t)(i*8)*K + k0, &As[wave*(MI*8) + i*8][0]);
    #pragma unroll
    for (int i=0;i<4;i++)
      GLL16(Bg + (size_t)(i*8)*K + k0, &Bs[wave*32 + i*8][0]);
    __syncthreads();
    bf16x8 af[2][MI], bfr[2][4];
    #pragma unroll
    for (int kk=0;kk<2;kk++){
      #pragma unroll
      for (int mi=0;mi<MI;mi++) af[kk][mi]  = *(const bf16x8*)&As[wm+mi*16+l15][8*((kk*4+quad) ^ rs)];
      #pragma unroll
      for (int ni=0;ni<4;ni++)  bfr[kk][ni] = *(const bf16x8*)&Bs[wn+ni*16+l15][8*((kk*4+quad) ^ rs)];
    }
    #pragma unroll
    for (int kk=0;kk<2;kk++)
      #pragma unroll
      for (int mi=0;mi<MI;mi++)
        #pragma unroll
        for (int ni=0;ni<4;ni++)
          acc[mi][ni] = __builtin_amdgcn_mfma_f32_16x16x32_bf16(af[kk][mi], bfr[kk][ni], acc[mi][ni],0,0,0);
    __syncthreads();
  }
  #pragma unroll
  for (int ni=0;ni<4;ni++){
    int col = n0 + wn + ni*16 + l15;
    float bv = 0.f; if (BIAS) bv = bias[col];
    #pragma unroll
    for (int mi=0;mi<MI;mi++){
      int rowb = m0 + wm + mi*16 + quad*4;
      #pragma unroll
      for (int r=0;r<4;r++){
        float v = acc[mi][ni][r] + bv;
        if (OUTBF) ((bf16_t*)Cv)[(size_t)(rowb+r)*N + col] = (bf16_t)v;
        else       ((float*)Cv)[(size_t)(rowb+r)*N + col]  = v;
      }
    }
  }
}

// ------- RoPE + head split (Q,K only): qkv bf16 [BT][3072] -> Q/K bf16 [B*H][T][64] -------
__global__ void k_rope(const bf16_t* __restrict__ qkv, bf16_t* __restrict__ Qb,
                       bf16_t* __restrict__ Kb){
  int p = blockIdx.x*blockDim.x + threadIdx.x;     // pair index over BT*1024
  int r = p >> 10;
  int c = (p & 1023)*2;                            // col in 0..2046 (q|k section)
  int s = c >> 10, rem = c & 1023;
  int h = rem >> 6, d = rem & 63, j = d >> 1;
  int b = r >> 11, t = r & 2047;
  float x1 = (float)qkv[(size_t)r*3072 + c];
  float x2 = (float)qkv[(size_t)r*3072 + c + 1];
  float freq = exp2f(-0.8304820237218406f * (float)(j & 15));
  float ang = (float)t * freq;
  float sn, cs;
  __sincosf(ang, &sn, &cs);
  float o1 = x1*cs - x2*sn;
  float o2 = x2*cs + x1*sn;
  bf16_t* dst = (s==0) ? Qb : Kb;
  bf16_t o[2] = {(bf16_t)o1, (bf16_t)o2};
  *(unsigned int*)(dst + (size_t)((b*NH + h)*NT + t)*HD + d) = *(const unsigned int*)o;
}

// ---------------- fused attention, swapped-QK^T layout ----------------
// mfma(K_frag, Q_frag): lane(quad,l15) holds S[q=l15][k=quad*4+r] -> lane-local
// k-runs: float4 attn stores, bf16x4 P stores, scalar lsum. K/V read directly
// from global (L2-resident per (b,h)); only wave-private Ps in LDS -> NO barriers.
__global__ __launch_bounds__(256) void k_attn(
    const bf16_t* __restrict__ Qb, const bf16_t* __restrict__ Kb, const bf16_t* __restrict__ Vtg,
    float* __restrict__ attn, bf16_t* __restrict__ Ob){
  __shared__ __align__(16) bf16_t Ps[4][16][64];  // per-wave P, XOR-swizzled 16B chunks
  int tid = threadIdx.x;
  int wave = tid>>6, lane = tid&63, quad = lane>>4, l15 = lane&15;
  int qt = blockIdx.x, bh = blockIdx.y;
  int h = bh & (NH-1);
  const float LOG2E = 1.4426950408889634f;
  float slope2 = exp2f(-0.5f*(float)(h+1)) * LOG2E;  // ALiBi slope, log2 domain
  const float c1 = 0.125f * LOG2E;                   // 1/sqrt(64) * log2(e)
  int qbase = qt*64 + wave*16;
  int qpos = qbase + l15;                            // this lane's q row
  const bf16_t* qrow = Qb + ((size_t)bh*NT + qpos)*HD;
  bf16x8 qa0 = *(const bf16x8*)(qrow + quad*8);
  bf16x8 qa1 = *(const bf16x8*)(qrow + 32 + quad*8);
  const bf16_t* kg = Kb  + (size_t)bh*NT*HD;         // K  [t][d]
  const bf16_t* vg = Vtg + (size_t)bh*HD*NT;         // V^T [d][t]
  const floatx4 z4 = {0.f,0.f,0.f,0.f};
  int rs = l15 & 7;
  char* psrow = (char*)&Ps[wave][l15][0];

  // ---- pass 1: row sums of exp2-domain scores (no-max trick: diag score >= 0) ----
  float lsum = 0.f;
  for (int k0=0;k0<NT;k0+=64){
    #pragma unroll
    for (int nt=0;nt<4;nt++){
      const bf16_t* kr = kg + (size_t)(k0+nt*16+l15)*HD + quad*8;
      bf16x8 ka0 = *(const bf16x8*)(kr);
      bf16x8 ka1 = *(const bf16x8*)(kr + 32);
      floatx4 sv = __builtin_amdgcn_mfma_f32_16x16x32_bf16(ka0, qa0, z4,0,0,0);
      sv = __builtin_amdgcn_mfma_f32_16x16x32_bf16(ka1, qa1, sv,0,0,0);
      float fk = (float)(qpos - (k0 + nt*16 + quad*4));
      #pragma unroll
      for (int r=0;r<4;r++){
        float arg = fmaf(sv[r], c1, -slope2*fabsf(fk - (float)r));
        lsum += exp2f(arg);
      }
    }
  }
  lsum += __shfl_xor(lsum, 16);
  lsum += __shfl_xor(lsum, 32);
  float li = -__log2f(lsum);                         // fold 1/lsum into exponent

  // ---- pass 2: recompute S, write normalized attn (floatx4), accumulate O = P V ----
  floatx4 oacc[4] = {z4,z4,z4,z4};
  float* attnrow = attn + (size_t)bh*NT*NT + (size_t)qpos*NT;
  for (int k0=0;k0<NT;k0+=64){
    #pragma unroll
    for (int nt=0;nt<4;nt++){
      const bf16_t* kr = kg + (size_t)(k0+nt*16+l15)*HD + quad*8;
      bf16x8 ka0 = *(const bf16x8*)(kr);
      bf16x8 ka1 = *(const bf16x8*)(kr + 32);
      floatx4 sv = __builtin_amdgcn_mfma_f32_16x16x32_bf16(ka0, qa0, z4,0,0,0);
      sv = __builtin_amdgcn_mfma_f32_16x16x32_bf16(ka1, qa1, sv,0,0,0);
      float fk = (float)(qpos - (k0 + nt*16 + quad*4));
      float p[4];
      #pragma unroll
      for (int r=0;r<4;r++){
        float arg = fmaf(sv[r], c1, fmaf(-slope2, fabsf(fk - (float)r), li));
        p[r] = exp2f(arg);
      }
      floatx4 st = {p[0],p[1],p[2],p[3]};
      __builtin_nontemporal_store(st, (floatx4*)(attnrow + k0 + nt*16 + quad*4));
      bf16x4 pb;
      #pragma unroll
      for (int r=0;r<4;r++) pb[r] = (bf16_t)p[r];
      // swizzled P store: logical 16B chunk c = nt*2+(quad>>1), half = quad&1
      *(bf16x4*)(psrow + (((nt*2 + (quad>>1)) ^ rs)*16 + (quad&1)*8)) = pb;
    }
    // PV: Ps is wave-private (same-wave LDS ordering) -> no barrier needed
    #pragma unroll
    for (int ks=0;ks<2;ks++){
      bf16x8 pa = *(const bf16x8*)(psrow + ((ks*4+quad) ^ rs)*16);
      #pragma unroll
      for (int dt=0;dt<4;dt++){
        bf16x8 vb = *(const bf16x8*)(vg + (size_t)(dt*16+l15)*NT + k0 + ks*32 + quad*8);
        oacc[dt] = __builtin_amdgcn_mfma_f32_16x16x32_bf16(pa, vb, oacc[dt],0,0,0);
      }
    }
  }
  int b = bh >> 4;
  #pragma unroll
  for (int dt=0;dt<4;dt++){
    #pragma unroll
    for (int r=0;r<4;r++){
      int t = qbase + quad*4 + r;
      Ob[(size_t)(b*NT + t)*NC + h*HD + dt*16 + l15] = (bf16_t)oacc[dt][r];
    }
  }
}

extern "C" void kernel_launch(void* const* d_in, const int* in_sizes, int n_in,
                              void* d_out, int out_size, void* d_ws, size_t ws_size,
                              hipStream_t stream){
  const float* x    = (const float*)d_in[0];
  const float* Wqkv = (const float*)d_in[1];
  const float* Wout = (const float*)d_in[2];
  const float* bout = (const float*)d_in[3];
  (void)in_sizes; (void)n_in; (void)out_size; (void)ws_size;

  char* ws = (char*)d_ws;
  size_t off = 0;
  auto alloc = [&](size_t elems)->bf16_t* {
    bf16_t* p = (bf16_t*)(ws + off);
    off += ((elems*sizeof(bf16_t) + 255)/256)*256;
    return p;
  };
  bf16_t* Xb   = alloc((size_t)BT*NC);        // x as bf16
  bf16_t* Wqt  = alloc((size_t)3*NC*NC);      // W_qkv^T bf16 [3072][1024]
  bf16_t* Wot  = alloc((size_t)NC*NC);        // W_out^T bf16 [1024][1024]
  bf16_t* QKVb = alloc((size_t)BT*3*NC);      // qkv bf16 [4096][3072]
  bf16_t* Qb   = alloc((size_t)NB*NH*NT*HD);  // post-RoPE, [b*h][t][d]
  bf16_t* Kb   = alloc((size_t)NB*NH*NT*HD);
  bf16_t* Vtg  = alloc((size_t)NB*NH*HD*NT);  // V^T, [b*h][d][t]
  bf16_t* Ob   = alloc((size_t)BT*NC);        // attention out, [b*t][h*d]

  k_cvt_x<<<(BT*NC/4)/256, 256, 0, stream>>>(x, Xb, BT*NC);
  k_cvt_t<<<dim3(3*NC/32, NC/32), 256, 0, stream>>>(Wqkv, Wqt, NC, 3*NC);
  k_cvt_t<<<dim3(NC/32,   NC/32), 256, 0, stream>>>(Wout, Wot, NC, NC);
  k_gemm<4,false,true><<<dim3(3*NC/128, BT/128), 256, 0, stream>>>(Xb, Wqt, (void*)QKVb, nullptr, BT, 3*NC, NC);
  k_rope<<<(BT*1024)/256, 256, 0, stream>>>(QKVb, Qb, Kb);
  k_trv<<<dim3(HD/32, NT/32, NB*NH), 256, 0, stream>>>(QKVb, Vtg);
  float* attn = (float*)d_out + (size_t)BT*NC;
  k_attn<<<dim3(NT/64, NB*NH), 256, 0, stream>>>(Qb, Kb, Vtg, attn, Ob);
  k_gemm<2,true,false><<<dim3(NC/128, BT/64), 256, 0, stream>>>(Ob, Wot, d_out, bout, BT, NC, NC);
}

// Round 18
// 747.792 us; speedup vs baseline: 1.2196x; 1.2196x over previous
//
#include <hip/hip_runtime.h>
#include <hip/hip_bf16.h>

typedef __bf16 bf16_t;
typedef __bf16 bf16x8 __attribute__((ext_vector_type(8)));
typedef __bf16 bf16x4 __attribute__((ext_vector_type(4)));
typedef float floatx4 __attribute__((ext_vector_type(4)));

#define NB 2
#define NT 2048
#define NC 1024
#define NH 16
#define HD 64
#define BT (NB*NT)

// async global->LDS, 16B per lane, LDS dest = wave-uniform base + lane*16
#define GLL16(g, l) __builtin_amdgcn_global_load_lds( \
    (const __attribute__((address_space(1))) void*)(g), \
    (__attribute__((address_space(3))) void*)(l), 16, 0, 0)

// ---------------- convert x: fp32 -> bf16 (row-major copy) ----------------
__global__ void k_cvt_x(const float* __restrict__ x, bf16_t* __restrict__ xb, int n){
  int i = (blockIdx.x*blockDim.x + threadIdx.x)*4;
  if (i >= n) return;
  float4 v = *(const float4*)(x+i);
  bf16_t o[4] = {(bf16_t)v.x,(bf16_t)v.y,(bf16_t)v.z,(bf16_t)v.w};
  *(uint2*)(xb+i) = *(const uint2*)o;
}

// ------- transpose-convert: in fp32 [K][N] -> out bf16 [N][K] (tiled) -------
__global__ void k_cvt_t(const float* __restrict__ in, bf16_t* __restrict__ out, int K, int N){
  __shared__ float tile[32][33];
  int tid = threadIdx.x;
  int kt = blockIdx.y*32, nt = blockIdx.x*32;
  int row = tid>>3, c4 = (tid&7)*4;
  float4 v = *(const float4*)(in + (size_t)(kt+row)*N + nt + c4);
  tile[row][c4+0]=v.x; tile[row][c4+1]=v.y; tile[row][c4+2]=v.z; tile[row][c4+3]=v.w;
  __syncthreads();
  bf16_t o[4];
  #pragma unroll
  for (int i=0;i<4;i++) o[i] = (bf16_t)tile[c4+i][row];
  *(uint2*)(out + (size_t)(nt+row)*K + kt + c4) = *(const uint2*)o;
}

// ---- bf16 transpose of the V block of qkv: [t][2048+h*64+d] -> Vt[bh][d][t] ----
__global__ void k_trv(const bf16_t* __restrict__ qkv, bf16_t* __restrict__ Vt){
  __shared__ float tile[32][33];
  int tid = threadIdx.x;
  int bh = blockIdx.z; int b = bh>>4, h = bh&15;
  int t0 = blockIdx.y*32, d0 = blockIdx.x*32;
  int row = tid>>3, c4 = (tid&7)*4;
  bf16x4 v = *(const bf16x4*)(qkv + (size_t)(b*NT + t0 + row)*3072 + 2048 + h*HD + d0 + c4);
  #pragma unroll
  for (int i=0;i<4;i++) tile[row][c4+i] = (float)v[i];
  __syncthreads();
  bf16x4 o;
  #pragma unroll
  for (int i=0;i<4;i++) o[i] = (bf16_t)tile[c4+i][row];
  *(bf16x4*)(Vt + ((size_t)bh*HD + d0 + row)*NT + t0 + c4) = o;
}

// ---------------- bf16 MFMA GEMM: C[M][N] = A[M][K] * Bt[N][K]^T ----------------
// m97-style: BMx128 tile (BM=MI*32), BK=64, 4 waves each (MI*16)x64,
// global_load_lds staging, XOR-swizzled LDS (slot ^= row&7) via pre-swizzled source.
template<int MI, bool BIAS, bool OUTBF>
__global__ __launch_bounds__(256) void k_gemm(
    const bf16_t* __restrict__ A, const bf16_t* __restrict__ Bt,
    void* __restrict__ Cv, const float* __restrict__ bias, int M, int N, int K){
  constexpr int BM = MI*32;
  __shared__ __align__(16) bf16_t As[BM][64];
  __shared__ __align__(16) bf16_t Bs[128][64];
  int tid = threadIdx.x;
  int wave = tid>>6, lane = tid&63, quad = lane>>4, l15 = lane&15;
  int m0 = blockIdx.y*BM, n0 = blockIdx.x*128;
  int wm = (wave>>1)*(MI*16), wn = (wave&1)*64;
  floatx4 acc[MI][4];
  #pragma unroll
  for(int i=0;i<MI;i++)
    #pragma unroll
    for(int j=0;j<4;j++) acc[i][j] = (floatx4){0.f,0.f,0.f,0.f};
  int srow = lane>>3;                 // row within 8-row chunk
  int sslot = (lane&7) ^ srow;        // pre-swizzled 16B slot in source
  const bf16_t* Ag = A  + (size_t)(m0 + wave*(MI*8) + srow)*K + sslot*8;
  const bf16_t* Bg = Bt + (size_t)(n0 + wave*32 + srow)*K + sslot*8;
  int rs = l15 & 7;
  for (int k0=0; k0<K; k0+=64){
    #pragma unroll
    for (int i=0;i<MI;i++)
      GLL16(Ag + (size_t)(i*8)*K + k0, &As[wave*(MI*8) + i*8][0]);
    #pragma unroll
    for (int i=0;i<4;i++)
      GLL16(Bg + (size_t)(i*8)*K + k0, &Bs[wave*32 + i*8][0]);
    __syncthreads();
    bf16x8 af[2][MI], bfr[2][4];
    #pragma unroll
    for (int kk=0;kk<2;kk++){
      #pragma unroll
      for (int mi=0;mi<MI;mi++) af[kk][mi]  = *(const bf16x8*)&As[wm+mi*16+l15][8*((kk*4+quad) ^ rs)];
      #pragma unroll
      for (int ni=0;ni<4;ni++)  bfr[kk][ni] = *(const bf16x8*)&Bs[wn+ni*16+l15][8*((kk*4+quad) ^ rs)];
    }
    #pragma unroll
    for (int kk=0;kk<2;kk++)
      #pragma unroll
      for (int mi=0;mi<MI;mi++)
        #pragma unroll
        for (int ni=0;ni<4;ni++)
          acc[mi][ni] = __builtin_amdgcn_mfma_f32_16x16x32_bf16(af[kk][mi], bfr[kk][ni], acc[mi][ni],0,0,0);
    __syncthreads();
  }
  #pragma unroll
  for (int ni=0;ni<4;ni++){
    int col = n0 + wn + ni*16 + l15;
    float bv = 0.f; if (BIAS) bv = bias[col];
    #pragma unroll
    for (int mi=0;mi<MI;mi++){
      int rowb = m0 + wm + mi*16 + quad*4;
      #pragma unroll
      for (int r=0;r<4;r++){
        float v = acc[mi][ni][r] + bv;
        if (OUTBF) ((bf16_t*)Cv)[(size_t)(rowb+r)*N + col] = (bf16_t)v;
        else       ((float*)Cv)[(size_t)(rowb+r)*N + col]  = v;
      }
    }
  }
}

// ------- RoPE + head split (Q,K only): qkv bf16 [BT][3072] -> Q/K bf16 [B*H][T][64] -------
__global__ void k_rope(const bf16_t* __restrict__ qkv, bf16_t* __restrict__ Qb,
                       bf16_t* __restrict__ Kb){
  int p = blockIdx.x*blockDim.x + threadIdx.x;     // pair index over BT*1024
  int r = p >> 10;
  int c = (p & 1023)*2;                            // col in 0..2046 (q|k section)
  int s = c >> 10, rem = c & 1023;
  int h = rem >> 6, d = rem & 63, j = d >> 1;
  int b = r >> 11, t = r & 2047;
  float x1 = (float)qkv[(size_t)r*3072 + c];
  float x2 = (float)qkv[(size_t)r*3072 + c + 1];
  float freq = exp2f(-0.8304820237218406f * (float)(j & 15));
  float ang = (float)t * freq;
  float sn, cs;
  __sincosf(ang, &sn, &cs);
  float o1 = x1*cs - x2*sn;
  float o2 = x2*cs + x1*sn;
  bf16_t* dst = (s==0) ? Qb : Kb;
  bf16_t o[2] = {(bf16_t)o1, (bf16_t)o2};
  *(unsigned int*)(dst + (size_t)((b*NH + h)*NT + t)*HD + d) = *(const unsigned int*)o;
}

// ---------------- fused attention: staged K/V + swapped-QK^T layout ----------------
// K,V^T staged via global_load_lds into XOR-swizzled LDS (round-2 proven path);
// mfma(K_frag, Q_frag): lane(quad,l15) holds S[q=l15][k=quad*4+r] -> lane-local
// k-runs: floatx4 nontemporal attn stores, bf16x4 Ps stores, scalar lsum,
// normalization folded into the exponent.
__global__ __launch_bounds__(256) void k_attn(
    const bf16_t* __restrict__ Qb, const bf16_t* __restrict__ Kb, const bf16_t* __restrict__ Vtg,
    float* __restrict__ attn, bf16_t* __restrict__ Ob){
  __shared__ __align__(16) bf16_t Ks[64][64];
  __shared__ __align__(16) bf16_t Vs[64][64];     // V^T tile: [d][key]
  __shared__ __align__(16) bf16_t Ps[4][16][64];  // per-wave P, XOR-swizzled 16B chunks
  int tid = threadIdx.x;
  int wave = tid>>6, lane = tid&63, quad = lane>>4, l15 = lane&15;
  int qt = blockIdx.x, bh = blockIdx.y;
  int h = bh & (NH-1);
  const float LOG2E = 1.4426950408889634f;
  float slope2 = exp2f(-0.5f*(float)(h+1)) * LOG2E;  // ALiBi slope, log2 domain
  const float c1 = 0.125f * LOG2E;                   // 1/sqrt(64) * log2(e)
  int qbase = qt*64 + wave*16;
  int qpos = qbase + l15;                            // this lane's q row
  const bf16_t* qrow = Qb + ((size_t)bh*NT + qpos)*HD;
  bf16x8 qa0 = *(const bf16x8*)(qrow + quad*8);
  bf16x8 qa1 = *(const bf16x8*)(qrow + 32 + quad*8);
  int srow = lane>>3, sslot = (lane&7) ^ srow;       // pre-swizzled staging source
  const bf16_t* kg = Kb  + ((size_t)bh*NT + wave*16 + srow)*HD + sslot*8;
  const bf16_t* vg = Vtg + ((size_t)bh*HD + wave*16 + srow)*NT + sslot*8;
  const floatx4 z4 = {0.f,0.f,0.f,0.f};
  int rs = l15 & 7;
  char* psrow = (char*)&Ps[wave][l15][0];

  // ---- pass 1: row sums of exp2-domain scores (no-max trick: diag score >= 0) ----
  float lsum = 0.f;
  for (int k0=0;k0<NT;k0+=64){
    #pragma unroll
    for (int i=0;i<2;i++)
      GLL16(kg + (size_t)(i*8)*HD + (size_t)k0*HD, &Ks[wave*16 + i*8][0]);
    __syncthreads();
    #pragma unroll
    for (int nt=0;nt<4;nt++){
      bf16x8 kb0 = *(const bf16x8*)&Ks[nt*16+l15][8*((quad)   ^ rs)];
      bf16x8 kb1 = *(const bf16x8*)&Ks[nt*16+l15][8*((4+quad) ^ rs)];
      floatx4 sv = __builtin_amdgcn_mfma_f32_16x16x32_bf16(kb0, qa0, z4,0,0,0);
      sv = __builtin_amdgcn_mfma_f32_16x16x32_bf16(kb1, qa1, sv,0,0,0);
      float fk = (float)(qpos - (k0 + nt*16 + quad*4));
      #pragma unroll
      for (int r=0;r<4;r++){
        float arg = fmaf(sv[r], c1, -slope2*fabsf(fk - (float)r));
        lsum += exp2f(arg);
      }
    }
    __syncthreads();
  }
  lsum += __shfl_xor(lsum, 16);
  lsum += __shfl_xor(lsum, 32);
  float li = -__log2f(lsum);                         // fold 1/lsum into exponent

  // ---- pass 2: recompute S, write normalized attn (floatx4), accumulate O = P V ----
  floatx4 oacc[4] = {z4,z4,z4,z4};
  float* attnrow = attn + (size_t)bh*NT*NT + (size_t)qpos*NT;
  for (int k0=0;k0<NT;k0+=64){
    #pragma unroll
    for (int i=0;i<2;i++){
      GLL16(kg + (size_t)(i*8)*HD + (size_t)k0*HD, &Ks[wave*16 + i*8][0]);
      GLL16(vg + (size_t)(i*8)*NT + k0,            &Vs[wave*16 + i*8][0]);
    }
    __syncthreads();
    #pragma unroll
    for (int nt=0;nt<4;nt++){
      bf16x8 kb0 = *(const bf16x8*)&Ks[nt*16+l15][8*((quad)   ^ rs)];
      bf16x8 kb1 = *(const bf16x8*)&Ks[nt*16+l15][8*((4+quad) ^ rs)];
      floatx4 sv = __builtin_amdgcn_mfma_f32_16x16x32_bf16(kb0, qa0, z4,0,0,0);
      sv = __builtin_amdgcn_mfma_f32_16x16x32_bf16(kb1, qa1, sv,0,0,0);
      float fk = (float)(qpos - (k0 + nt*16 + quad*4));
      float p[4];
      #pragma unroll
      for (int r=0;r<4;r++){
        float arg = fmaf(sv[r], c1, fmaf(-slope2, fabsf(fk - (float)r), li));
        p[r] = exp2f(arg);
      }
      floatx4 st = {p[0],p[1],p[2],p[3]};
      __builtin_nontemporal_store(st, (floatx4*)(attnrow + k0 + nt*16 + quad*4));
      bf16x4 pb;
      #pragma unroll
      for (int r=0;r<4;r++) pb[r] = (bf16_t)p[r];
      // swizzled P store: logical 16B chunk c = nt*2+(quad>>1), half = quad&1
      *(bf16x4*)(psrow + (((nt*2 + (quad>>1)) ^ rs)*16 + (quad&1)*8)) = pb;
    }
    // PV: Ps is wave-private (same-wave LDS ordering) -> no barrier needed here
    #pragma unroll
    for (int ks=0;ks<2;ks++){
      bf16x8 pa = *(const bf16x8*)(psrow + ((ks*4+quad) ^ rs)*16);
      #pragma unroll
      for (int dt=0;dt<4;dt++){
        bf16x8 vb = *(const bf16x8*)&Vs[dt*16+l15][8*((ks*4+quad) ^ rs)];
        oacc[dt] = __builtin_amdgcn_mfma_f32_16x16x32_bf16(pa, vb, oacc[dt],0,0,0);
      }
    }
    __syncthreads();                                 // done with Ks/Vs
  }
  int b = bh >> 4;
  #pragma unroll
  for (int dt=0;dt<4;dt++){
    #pragma unroll
    for (int r=0;r<4;r++){
      int t = qbase + quad*4 + r;
      Ob[(size_t)(b*NT + t)*NC + h*HD + dt*16 + l15] = (bf16_t)oacc[dt][r];
    }
  }
}

extern "C" void kernel_launch(void* const* d_in, const int* in_sizes, int n_in,
                              void* d_out, int out_size, void* d_ws, size_t ws_size,
                              hipStream_t stream){
  const float* x    = (const float*)d_in[0];
  const float* Wqkv = (const float*)d_in[1];
  const float* Wout = (const float*)d_in[2];
  const float* bout = (const float*)d_in[3];
  (void)in_sizes; (void)n_in; (void)out_size; (void)ws_size;

  char* ws = (char*)d_ws;
  size_t off = 0;
  auto alloc = [&](size_t elems)->bf16_t* {
    bf16_t* p = (bf16_t*)(ws + off);
    off += ((elems*sizeof(bf16_t) + 255)/256)*256;
    return p;
  };
  bf16_t* Xb   = alloc((size_t)BT*NC);        // x as bf16
  bf16_t* Wqt  = alloc((size_t)3*NC*NC);      // W_qkv^T bf16 [3072][1024]
  bf16_t* Wot  = alloc((size_t)NC*NC);        // W_out^T bf16 [1024][1024]
  bf16_t* QKVb = alloc((size_t)BT*3*NC);      // qkv bf16 [4096][3072]
  bf16_t* Qb   = alloc((size_t)NB*NH*NT*HD);  // post-RoPE, [b*h][t][d]
  bf16_t* Kb   = alloc((size_t)NB*NH*NT*HD);
  bf16_t* Vtg  = alloc((size_t)NB*NH*HD*NT);  // V^T, [b*h][d][t]
  bf16_t* Ob   = alloc((size_t)BT*NC);        // attention out, [b*t][h*d]

  k_cvt_x<<<(BT*NC/4)/256, 256, 0, stream>>>(x, Xb, BT*NC);
  k_cvt_t<<<dim3(3*NC/32, NC/32), 256, 0, stream>>>(Wqkv, Wqt, NC, 3*NC);
  k_cvt_t<<<dim3(NC/32,   NC/32), 256, 0, stream>>>(Wout, Wot, NC, NC);
  k_gemm<4,false,true><<<dim3(3*NC/128, BT/128), 256, 0, stream>>>(Xb, Wqt, (void*)QKVb, nullptr, BT, 3*NC, NC);
  k_rope<<<(BT*1024)/256, 256, 0, stream>>>(QKVb, Qb, Kb);
  k_trv<<<dim3(HD/32, NT/32, NB*NH), 256, 0, stream>>>(QKVb, Vtg);
  float* attn = (float*)d_out + (size_t)BT*NC;
  k_attn<<<dim3(NT/64, NB*NH), 256, 0, stream>>>(Qb, Kb, Vtg, attn, Ob);
  k_gemm<2,true,false><<<dim3(NC/128, BT/64), 256, 0, stream>>>(Ob, Wot, d_out, bout, BT, NC, NC);
}